// Round 5
// baseline (93.376 us; speedup 1.0000x reference)
//
#include <hip/hip_runtime.h>
#include <math.h>

// Problem constants: B=2, C=16, D=64, H=128, W=128, K=4
#define SPATIAL (64 * 128 * 128)   // 2^20 voxels per sample
#define NCLS 16
#define NB 2
#define NBLK 2048                  // 2048 blocks * 256 thr * 4 vox = 2*SPATIAL exactly
#define TPB 256

// Fused: R3's proven streaming loop (chunked double-buffered prefetch, 4 classes
// ahead) + last-block-ticket finalize (saves the serialized bce_final launch).
// R2's 4x regression was the float4[16] scratch spill, NOT the ticket pattern.
__global__ __launch_bounds__(TPB) void bce_fused(
    const float* __restrict__ probs,     // [B, C, SPATIAL]
    const int*   __restrict__ target,    // [B, SPATIAL]
    const int*   __restrict__ ann,       // [B, 4]
    float*       __restrict__ partials,  // [5][NBLK] in d_ws
    unsigned*    __restrict__ counter,   // 1 uint in d_ws, zeroed per launch
    float*       __restrict__ out)       // out[0]=ce, out[1]=reg
{
    const int j = blockIdx.x * TPB + threadIdx.x;
    const int v = j * 4;                 // first voxel
    const int b = v >> 20;               // sample (SPATIAL = 2^20); wave-uniform
    const int s = v & (SPATIAL - 1);

    const int4 t4 = *reinterpret_cast<const int4*>(target + v);
    const int t[4] = {t4.x, t4.y, t4.z, t4.w};

    // Unannotated-class bitmask (class 0 never annotated as fg); wave-uniform.
    unsigned a = 0;
#pragma unroll
    for (int k = 0; k < 4; ++k) {
        const int c = ann[b * 4 + k];
        if (c > 0) a |= (1u << c);
    }
    const unsigned m = ~a & 0xFFFFu;

    const float* pb = probs + (size_t)b * NCLS * SPATIAL + s;

    float ent[4] = {0.f, 0.f, 0.f, 0.f};
    float s0[4]  = {0.f, 0.f, 0.f, 0.f};
    float pt[4]  = {0.f, 0.f, 0.f, 0.f};

    // Pipeline: buf[2][4], chunk = 4 classes. All indices compile-time constant.
    float4 buf[2][4];
#pragma unroll
    for (int c = 0; c < 4; ++c)
        buf[0][c] = *reinterpret_cast<const float4*>(pb + (size_t)c * SPATIAL);

#pragma unroll
    for (int ch = 0; ch < 4; ++ch) {
        const int cur = ch & 1, nxt = cur ^ 1;
        if (ch < 3) {
#pragma unroll
            for (int c = 0; c < 4; ++c)
                buf[nxt][c] = *reinterpret_cast<const float4*>(
                    pb + (size_t)((ch + 1) * 4 + c) * SPATIAL);
        }
#pragma unroll
        for (int c = 0; c < 4; ++c) {
            const int cls = ch * 4 + c;
            const float p[4] = {buf[cur][c].x, buf[cur][c].y, buf[cur][c].z, buf[cur][c].w};
            const bool un = (m >> cls) & 1u;
#pragma unroll
            for (int q = 0; q < 4; ++q) {
                const float pc = fminf(fmaxf(p[q], 1e-6f), 0.999999f);
                ent[q] = fmaf(p[q], __log2f(pc), ent[q]);
                if (un) s0[q] += p[q];
                if (cls == t[q]) pt[q] = p[q];
            }
        }
    }

    float ce_sum = 0.f, ent_b = 0.f, cnt_b = 0.f;
#pragma unroll
    for (int q = 0; q < 4; ++q) {
        const float p  = (t[q] > 0) ? pt[q] : s0[q];
        const float pc = fminf(fmaxf(p, 1e-6f), 0.999999f);
        const float om = 1.f - p;                   // focal uses UNclamped p
        ce_sum += om * om * __log2f(pc);
        ent_b  += ent[q];
        cnt_b  += (t[q] != 0) ? 1.f : 0.f;
    }

    float vals[5];
    vals[0] = ce_sum;
    vals[1] = (b == 0) ? ent_b : 0.f;
    vals[2] = (b == 1) ? ent_b : 0.f;
    vals[3] = (b == 0) ? cnt_b : 0.f;
    vals[4] = (b == 1) ? cnt_b : 0.f;

    __shared__ float red[5][TPB / 64];
    __shared__ int   lastFlag;
    const int lane = threadIdx.x & 63;
    const int wave = threadIdx.x >> 6;
#pragma unroll
    for (int qq = 0; qq < 5; ++qq) {
        float x = vals[qq];
#pragma unroll
        for (int off = 32; off > 0; off >>= 1)
            x += __shfl_down(x, off, 64);
        if (lane == 0) red[qq][wave] = x;
    }
    __syncthreads();
    if (threadIdx.x == 0) {
#pragma unroll
        for (int qq = 0; qq < 5; ++qq) {
            float x = 0.f;
#pragma unroll
            for (int w = 0; w < TPB / 64; ++w) x += red[qq][w];
            __hip_atomic_store(&partials[qq * NBLK + blockIdx.x], x,
                               __ATOMIC_RELAXED, __HIP_MEMORY_SCOPE_AGENT);
        }
        __threadfence();                              // release partials (device scope)
        const unsigned old = atomicAdd(counter, 1u);  // device-scope ticket
        lastFlag = (old == NBLK - 1) ? 1 : 0;
    }
    __syncthreads();
    if (!lastFlag) return;

    // ---- last block, wave 0 only: barrier-free float4 shuffle-tree finalize ----
    if (threadIdx.x >= 64) return;
    __threadfence();                                  // acquire

    float acc[5] = {0.f, 0.f, 0.f, 0.f, 0.f};
#pragma unroll
    for (int qq = 0; qq < 5; ++qq) {
        const float4* src = reinterpret_cast<const float4*>(partials + qq * NBLK);
#pragma unroll
        for (int i = 0; i < 8; ++i) {
            const float4 x = src[i * 64 + lane];
            acc[qq] += (x.x + x.y) + (x.z + x.w);
        }
    }
#pragma unroll
    for (int qq = 0; qq < 5; ++qq) {
#pragma unroll
        for (int off = 32; off > 0; off >>= 1)
            acc[qq] += __shfl_down(acc[qq], off, 64);
    }
    if (lane == 0) {
        const float ce = acc[0], e0 = acc[1], e1 = acc[2], c0 = acc[3], c1 = acc[4];
        const float LN2  = 0.69314718055994530942f;
        const float invS = 1.f / (float)SPATIAL;
        const float ent0 = e0 * LN2 * invS;
        const float ent1 = e1 * LN2 * invS;
        const float m0   = (c0 == 0.f) ? 3.f : 1.f;   // all_bg -> MULT_UNLABELED
        const float m1   = (c1 == 0.f) ? 3.f : 1.f;
        out[0] = -(ce * LN2) / (float)(NB * SPATIAL);
        out[1] = -(m0 * ent0 + m1 * ent1) * 0.5f;
    }
}

extern "C" void kernel_launch(void* const* d_in, const int* in_sizes, int n_in,
                              void* d_out, int out_size, void* d_ws, size_t ws_size,
                              hipStream_t stream) {
    const float* probs  = (const float*)d_in[0];
    const int*   target = (const int*)d_in[1];
    const int*   ann    = (const int*)d_in[2];
    float*       out    = (float*)d_out;

    float*    partials = (float*)d_ws;                         // 5*NBLK*4 = 40 KiB
    unsigned* counter  = (unsigned*)((char*)d_ws + 5 * NBLK * sizeof(float));

    (void)hipMemsetAsync(counter, 0, sizeof(unsigned), stream); // graph-safe ticket reset
    bce_fused<<<NBLK, TPB, 0, stream>>>(probs, target, ann, partials, counter, out);
}

// Round 6
// 55.818 us; speedup vs baseline: 1.6729x; 1.6729x over previous
//
#include <hip/hip_runtime.h>
#include <math.h>

// Problem constants: B=2, C=16, D=64, H=128, W=128, K=4
#define SPATIAL (64 * 128 * 128)   // 2^20 voxels per sample
#define NCLS 16
#define NB 2
#define NBLK 1024                  // 1024 blocks * 256 thr * 8 vox = 2*SPATIAL exactly
#define TPB 256

// Two-kernel structure (R3, proven): fused device-scope ticket finalize measured
// +120us fixed cost (R2/R5) -- do NOT fuse. Main pass: 8 voxels/thread,
// 2x float4 per class (2KB contiguous per wave per class-plane), chunked
// double-buffered prefetch of 2 classes (8 float4 in flight).
__global__ __launch_bounds__(TPB) void bce_main(
    const float* __restrict__ probs,    // [B, C, SPATIAL]
    const int*   __restrict__ target,   // [B, SPATIAL]
    const int*   __restrict__ ann,      // [B, 4]
    float*       __restrict__ partials) // [5][NBLK]
{
    const int j = blockIdx.x * TPB + threadIdx.x;
    const int v = j * 8;                 // first of 8 consecutive voxels
    const int b = v >> 20;               // sample; never straddles (2^20 % 8 == 0)
    const int s = v & (SPATIAL - 1);

    const int4 t4a = *reinterpret_cast<const int4*>(target + v);
    const int4 t4b = *reinterpret_cast<const int4*>(target + v + 4);
    const int t[8] = {t4a.x, t4a.y, t4a.z, t4a.w, t4b.x, t4b.y, t4b.z, t4b.w};

    // Unannotated-class bitmask (class 0 never annotated as fg); wave-uniform.
    unsigned a = 0;
#pragma unroll
    for (int k = 0; k < 4; ++k) {
        const int c = ann[b * 4 + k];
        if (c > 0) a |= (1u << c);
    }
    const unsigned m = ~a & 0xFFFFu;

    const float* pb = probs + (size_t)b * NCLS * SPATIAL + s;

    float ent[8], s0[8], pt[8];
#pragma unroll
    for (int q = 0; q < 8; ++q) { ent[q] = 0.f; s0[q] = 0.f; pt[q] = 0.f; }

    // Pipeline: buf[2][2][2] = double-buffer x 2 classes/chunk x 2 float4/class.
    // All indices compile-time constant (rule: no runtime-indexed vector arrays).
    float4 buf[2][2][2];
#pragma unroll
    for (int c = 0; c < 2; ++c) {
        buf[0][c][0] = *reinterpret_cast<const float4*>(pb + (size_t)c * SPATIAL);
        buf[0][c][1] = *reinterpret_cast<const float4*>(pb + (size_t)c * SPATIAL + 4);
    }

#pragma unroll
    for (int ch = 0; ch < 8; ++ch) {       // 8 chunks x 2 classes = 16 classes
        const int cur = ch & 1, nxt = cur ^ 1;
        if (ch < 7) {
#pragma unroll
            for (int c = 0; c < 2; ++c) {
                const size_t off = (size_t)((ch + 1) * 2 + c) * SPATIAL;
                buf[nxt][c][0] = *reinterpret_cast<const float4*>(pb + off);
                buf[nxt][c][1] = *reinterpret_cast<const float4*>(pb + off + 4);
            }
        }
#pragma unroll
        for (int c = 0; c < 2; ++c) {
            const int cls = ch * 2 + c;
            const float p[8] = {buf[cur][c][0].x, buf[cur][c][0].y,
                                buf[cur][c][0].z, buf[cur][c][0].w,
                                buf[cur][c][1].x, buf[cur][c][1].y,
                                buf[cur][c][1].z, buf[cur][c][1].w};
            const bool un = (m >> cls) & 1u;
#pragma unroll
            for (int q = 0; q < 8; ++q) {
                const float pc = fminf(fmaxf(p[q], 1e-6f), 0.999999f);
                ent[q] = fmaf(p[q], __log2f(pc), ent[q]);
                if (un) s0[q] += p[q];
                if (cls == t[q]) pt[q] = p[q];
            }
        }
    }

    float ce_sum = 0.f, ent_b = 0.f, cnt_b = 0.f;
#pragma unroll
    for (int q = 0; q < 8; ++q) {
        const float p  = (t[q] > 0) ? pt[q] : s0[q];
        const float pc = fminf(fmaxf(p, 1e-6f), 0.999999f);
        const float om = 1.f - p;                   // focal uses UNclamped p
        ce_sum += om * om * __log2f(pc);
        ent_b  += ent[q];
        cnt_b  += (t[q] != 0) ? 1.f : 0.f;
    }

    float vals[5];
    vals[0] = ce_sum;
    vals[1] = (b == 0) ? ent_b : 0.f;
    vals[2] = (b == 1) ? ent_b : 0.f;
    vals[3] = (b == 0) ? cnt_b : 0.f;
    vals[4] = (b == 1) ? cnt_b : 0.f;

    __shared__ float red[5][TPB / 64];
    const int lane = threadIdx.x & 63;
    const int wave = threadIdx.x >> 6;
#pragma unroll
    for (int qq = 0; qq < 5; ++qq) {
        float x = vals[qq];
#pragma unroll
        for (int off = 32; off > 0; off >>= 1)
            x += __shfl_down(x, off, 64);
        if (lane == 0) red[qq][wave] = x;
    }
    __syncthreads();
    if (threadIdx.x == 0) {
#pragma unroll
        for (int qq = 0; qq < 5; ++qq) {
            float x = 0.f;
#pragma unroll
            for (int w = 0; w < TPB / 64; ++w) x += red[qq][w];
            partials[qq * NBLK + blockIdx.x] = x;
        }
    }
}

// ---------------- finalize: single wave, no barriers, float4 reads ----------------
__global__ __launch_bounds__(64) void bce_final(
    const float* __restrict__ partials, float* __restrict__ out)
{
    const int lane = threadIdx.x;   // 64 threads = 1 wave
    // Each quantity stream: 1024 floats = 64 lanes * 4 float4.
    float acc[5] = {0.f, 0.f, 0.f, 0.f, 0.f};
#pragma unroll
    for (int qq = 0; qq < 5; ++qq) {
        const float4* src = reinterpret_cast<const float4*>(partials + qq * NBLK);
#pragma unroll
        for (int i = 0; i < 4; ++i) {
            const float4 x = src[i * 64 + lane];
            acc[qq] += (x.x + x.y) + (x.z + x.w);
        }
    }
#pragma unroll
    for (int qq = 0; qq < 5; ++qq) {
#pragma unroll
        for (int off = 32; off > 0; off >>= 1)
            acc[qq] += __shfl_down(acc[qq], off, 64);
    }
    if (lane == 0) {
        const float ce = acc[0], e0 = acc[1], e1 = acc[2], c0 = acc[3], c1 = acc[4];
        const float LN2  = 0.69314718055994530942f;
        const float invS = 1.f / (float)SPATIAL;
        const float ent0 = e0 * LN2 * invS;
        const float ent1 = e1 * LN2 * invS;
        const float m0   = (c0 == 0.f) ? 3.f : 1.f;   // all_bg -> MULT_UNLABELED
        const float m1   = (c1 == 0.f) ? 3.f : 1.f;
        out[0] = -(ce * LN2) / (float)(NB * SPATIAL);
        out[1] = -(m0 * ent0 + m1 * ent1) * 0.5f;
    }
}

extern "C" void kernel_launch(void* const* d_in, const int* in_sizes, int n_in,
                              void* d_out, int out_size, void* d_ws, size_t ws_size,
                              hipStream_t stream) {
    const float* probs  = (const float*)d_in[0];
    const int*   target = (const int*)d_in[1];
    const int*   ann    = (const int*)d_in[2];
    float*       out    = (float*)d_out;
    float*       partials = (float*)d_ws;   // 5 * NBLK * 4 B = 20 KiB

    bce_main<<<NBLK, TPB, 0, stream>>>(probs, target, ann, partials);
    bce_final<<<1, 64, 0, stream>>>(partials, out);
}

// Round 7
// 36.095 us; speedup vs baseline: 2.5869x; 1.5464x over previous
//
#include <hip/hip_runtime.h>
#include <math.h>

// Problem constants: B=2, C=16, D=64, H=128, W=128, K=4
#define SPATIAL (64 * 128 * 128)   // 2^20 voxels per sample
#define NCLS 16
#define NB 2
#define NBLK 2048                  // 2048 blocks * 256 thr * 4 vox = 2*SPATIAL exactly
#define TPB 256

// R3 structure (proven best, 36.9us) + per-block class-chunk rotation:
// chunk' = (ch + blockIdx&3) & 3. Class sums commute, so results are identical;
// rotation decorrelates the device-wide same-offset 16-plane (4MiB-stride)
// load bursts that are the suspected ~4.3 TB/s BW cap.
// Fused ticket finalize measured +120us fixed (R2/R5) -- keep 2 kernels.
// float4[16] front-load spills to scratch (R2) -- keep depth-8 double buffer.
__global__ __launch_bounds__(TPB) void bce_main(
    const float* __restrict__ probs,    // [B, C, SPATIAL]
    const int*   __restrict__ target,   // [B, SPATIAL]
    const int*   __restrict__ ann,      // [B, 4]
    float*       __restrict__ partials) // [5][NBLK]
{
    const int j = blockIdx.x * TPB + threadIdx.x;
    const int v = j * 4;                 // first voxel
    const int b = v >> 20;               // sample (SPATIAL = 2^20); wave-uniform
    const int s = v & (SPATIAL - 1);
    const int rot = blockIdx.x & 3;      // class-chunk rotation

    const int4 t4 = *reinterpret_cast<const int4*>(target + v);
    const int t[4] = {t4.x, t4.y, t4.z, t4.w};

    // Unannotated-class bitmask (class 0 never annotated as fg); wave-uniform.
    unsigned a = 0;
#pragma unroll
    for (int k = 0; k < 4; ++k) {
        const int c = ann[b * 4 + k];
        if (c > 0) a |= (1u << c);
    }
    const unsigned m = ~a & 0xFFFFu;

    const float* pb = probs + (size_t)b * NCLS * SPATIAL + s;

    float ent[4] = {0.f, 0.f, 0.f, 0.f};
    float s0[4]  = {0.f, 0.f, 0.f, 0.f};
    float pt[4]  = {0.f, 0.f, 0.f, 0.f};

    // Pipeline: buf[2][4], chunk = 4 classes, rotated start. Indices static.
    float4 buf[2][4];
    {
        const int ck0 = rot;  // (0 + rot) & 3
#pragma unroll
        for (int c = 0; c < 4; ++c)
            buf[0][c] = *reinterpret_cast<const float4*>(
                pb + (size_t)(ck0 * 4 + c) * SPATIAL);
    }

#pragma unroll
    for (int ch = 0; ch < 4; ++ch) {
        const int cur = ch & 1, nxt = cur ^ 1;
        if (ch < 3) {
            const int ckn = (ch + 1 + rot) & 3;
#pragma unroll
            for (int c = 0; c < 4; ++c)
                buf[nxt][c] = *reinterpret_cast<const float4*>(
                    pb + (size_t)(ckn * 4 + c) * SPATIAL);
        }
        const int ck = (ch + rot) & 3;
#pragma unroll
        for (int c = 0; c < 4; ++c) {
            const int cls = ck * 4 + c;
            const float p[4] = {buf[cur][c].x, buf[cur][c].y, buf[cur][c].z, buf[cur][c].w};
            const bool un = (m >> cls) & 1u;
#pragma unroll
            for (int q = 0; q < 4; ++q) {
                const float pc = fminf(fmaxf(p[q], 1e-6f), 0.999999f);
                ent[q] = fmaf(p[q], __log2f(pc), ent[q]);
                if (un) s0[q] += p[q];
                if (cls == t[q]) pt[q] = p[q];
            }
        }
    }

    float ce_sum = 0.f, ent_b = 0.f, cnt_b = 0.f;
#pragma unroll
    for (int q = 0; q < 4; ++q) {
        const float p  = (t[q] > 0) ? pt[q] : s0[q];
        const float pc = fminf(fmaxf(p, 1e-6f), 0.999999f);
        const float om = 1.f - p;                   // focal uses UNclamped p
        ce_sum += om * om * __log2f(pc);
        ent_b  += ent[q];
        cnt_b  += (t[q] != 0) ? 1.f : 0.f;
    }

    float vals[5];
    vals[0] = ce_sum;
    vals[1] = (b == 0) ? ent_b : 0.f;
    vals[2] = (b == 1) ? ent_b : 0.f;
    vals[3] = (b == 0) ? cnt_b : 0.f;
    vals[4] = (b == 1) ? cnt_b : 0.f;

    __shared__ float red[5][TPB / 64];
    const int lane = threadIdx.x & 63;
    const int wave = threadIdx.x >> 6;
#pragma unroll
    for (int qq = 0; qq < 5; ++qq) {
        float x = vals[qq];
#pragma unroll
        for (int off = 32; off > 0; off >>= 1)
            x += __shfl_down(x, off, 64);
        if (lane == 0) red[qq][wave] = x;
    }
    __syncthreads();
    if (threadIdx.x == 0) {
#pragma unroll
        for (int qq = 0; qq < 5; ++qq) {
            float x = 0.f;
#pragma unroll
            for (int w = 0; w < TPB / 64; ++w) x += red[qq][w];
            partials[qq * NBLK + blockIdx.x] = x;
        }
    }
}

// ---------------- finalize: single wave, no barriers, float4 reads ----------------
__global__ __launch_bounds__(64) void bce_final(
    const float* __restrict__ partials, float* __restrict__ out)
{
    const int lane = threadIdx.x;   // 64 threads = 1 wave
    float acc[5] = {0.f, 0.f, 0.f, 0.f, 0.f};
#pragma unroll
    for (int qq = 0; qq < 5; ++qq) {
        const float4* src = reinterpret_cast<const float4*>(partials + qq * NBLK);
#pragma unroll
        for (int i = 0; i < 8; ++i) {
            const float4 x = src[i * 64 + lane];
            acc[qq] += (x.x + x.y) + (x.z + x.w);
        }
    }
#pragma unroll
    for (int qq = 0; qq < 5; ++qq) {
#pragma unroll
        for (int off = 32; off > 0; off >>= 1)
            acc[qq] += __shfl_down(acc[qq], off, 64);
    }
    if (lane == 0) {
        const float ce = acc[0], e0 = acc[1], e1 = acc[2], c0 = acc[3], c1 = acc[4];
        const float LN2  = 0.69314718055994530942f;
        const float invS = 1.f / (float)SPATIAL;
        const float ent0 = e0 * LN2 * invS;
        const float ent1 = e1 * LN2 * invS;
        const float m0   = (c0 == 0.f) ? 3.f : 1.f;   // all_bg -> MULT_UNLABELED
        const float m1   = (c1 == 0.f) ? 3.f : 1.f;
        out[0] = -(ce * LN2) / (float)(NB * SPATIAL);
        out[1] = -(m0 * ent0 + m1 * ent1) * 0.5f;
    }
}

extern "C" void kernel_launch(void* const* d_in, const int* in_sizes, int n_in,
                              void* d_out, int out_size, void* d_ws, size_t ws_size,
                              hipStream_t stream) {
    const float* probs  = (const float*)d_in[0];
    const int*   target = (const int*)d_in[1];
    const int*   ann    = (const int*)d_in[2];
    float*       out    = (float*)d_out;
    float*       partials = (float*)d_ws;   // 5 * NBLK * 4 B = 40 KiB

    bce_main<<<NBLK, TPB, 0, stream>>>(probs, target, ann, partials);
    bce_final<<<1, 64, 0, stream>>>(partials, out);
}

// Round 9
// 33.746 us; speedup vs baseline: 2.7670x; 1.0696x over previous
//
#include <hip/hip_runtime.h>
#include <math.h>

// Problem constants: B=2, C=16, D=64, H=128, W=128, K=4
#define SPATIAL (64 * 128 * 128)   // 2^20 voxels per sample
#define NCLS 16
#define NB 2
#define NBLK 2048                  // 2048 blocks * 256 thr * 4 vox = 2*SPATIAL exactly
#define TPB 256

// Ledger: fused ticket finalize = +120us fixed (R2/R5) -> keep 2 kernels.
// float4[16] front-load -> scratch spill (R2). 8 vox/thread halves occupancy
// -> latency-bound 77us (R6). Chunk rotation: null (R7). This round:
// nontemporal loads via native clang vectors (HIP_vector_type rejected, R8).

typedef float  f32x4 __attribute__((ext_vector_type(4)));
typedef int    i32x4 __attribute__((ext_vector_type(4)));

__device__ __forceinline__ f32x4 ntload4(const float* p) {
    return __builtin_nontemporal_load(reinterpret_cast<const f32x4*>(p));
}
__device__ __forceinline__ i32x4 ntload4i(const int* p) {
    return __builtin_nontemporal_load(reinterpret_cast<const i32x4*>(p));
}

__global__ __launch_bounds__(TPB) void bce_main(
    const float* __restrict__ probs,    // [B, C, SPATIAL]
    const int*   __restrict__ target,   // [B, SPATIAL]
    const int*   __restrict__ ann,      // [B, 4]
    float*       __restrict__ partials) // [5][NBLK]
{
    const int j = blockIdx.x * TPB + threadIdx.x;
    const int v = j * 4;                 // first voxel
    const int b = v >> 20;               // sample (SPATIAL = 2^20); wave-uniform
    const int s = v & (SPATIAL - 1);
    const int rot = blockIdx.x & 3;      // class-chunk rotation (free, kept)

    const i32x4 t4 = ntload4i(target + v);
    const int t[4] = {t4.x, t4.y, t4.z, t4.w};

    // Unannotated-class bitmask (class 0 never annotated as fg); wave-uniform.
    unsigned a = 0;
#pragma unroll
    for (int k = 0; k < 4; ++k) {
        const int c = ann[b * 4 + k];
        if (c > 0) a |= (1u << c);
    }
    const unsigned m = ~a & 0xFFFFu;

    const float* pb = probs + (size_t)b * NCLS * SPATIAL + s;

    float ent[4] = {0.f, 0.f, 0.f, 0.f};
    float s0[4]  = {0.f, 0.f, 0.f, 0.f};
    float pt[4]  = {0.f, 0.f, 0.f, 0.f};

    // Pipeline: buf[2][4], chunk = 4 classes, rotated start. Indices static.
    f32x4 buf[2][4];
    {
        const int ck0 = rot;
#pragma unroll
        for (int c = 0; c < 4; ++c)
            buf[0][c] = ntload4(pb + (size_t)(ck0 * 4 + c) * SPATIAL);
    }

#pragma unroll
    for (int ch = 0; ch < 4; ++ch) {
        const int cur = ch & 1, nxt = cur ^ 1;
        if (ch < 3) {
            const int ckn = (ch + 1 + rot) & 3;
#pragma unroll
            for (int c = 0; c < 4; ++c)
                buf[nxt][c] = ntload4(pb + (size_t)(ckn * 4 + c) * SPATIAL);
        }
        const int ck = (ch + rot) & 3;
#pragma unroll
        for (int c = 0; c < 4; ++c) {
            const int cls = ck * 4 + c;
            const float p[4] = {buf[cur][c].x, buf[cur][c].y, buf[cur][c].z, buf[cur][c].w};
            const bool un = (m >> cls) & 1u;
#pragma unroll
            for (int q = 0; q < 4; ++q) {
                const float pc = fminf(fmaxf(p[q], 1e-6f), 0.999999f);
                ent[q] = fmaf(p[q], __log2f(pc), ent[q]);
                if (un) s0[q] += p[q];
                if (cls == t[q]) pt[q] = p[q];
            }
        }
    }

    float ce_sum = 0.f, ent_b = 0.f, cnt_b = 0.f;
#pragma unroll
    for (int q = 0; q < 4; ++q) {
        const float p  = (t[q] > 0) ? pt[q] : s0[q];
        const float pc = fminf(fmaxf(p, 1e-6f), 0.999999f);
        const float om = 1.f - p;                   // focal uses UNclamped p
        ce_sum += om * om * __log2f(pc);
        ent_b  += ent[q];
        cnt_b  += (t[q] != 0) ? 1.f : 0.f;
    }

    float vals[5];
    vals[0] = ce_sum;
    vals[1] = (b == 0) ? ent_b : 0.f;
    vals[2] = (b == 1) ? ent_b : 0.f;
    vals[3] = (b == 0) ? cnt_b : 0.f;
    vals[4] = (b == 1) ? cnt_b : 0.f;

    __shared__ float red[5][TPB / 64];
    const int lane = threadIdx.x & 63;
    const int wave = threadIdx.x >> 6;
#pragma unroll
    for (int qq = 0; qq < 5; ++qq) {
        float x = vals[qq];
#pragma unroll
        for (int off = 32; off > 0; off >>= 1)
            x += __shfl_down(x, off, 64);
        if (lane == 0) red[qq][wave] = x;
    }
    __syncthreads();
    if (threadIdx.x == 0) {
#pragma unroll
        for (int qq = 0; qq < 5; ++qq) {
            float x = 0.f;
#pragma unroll
            for (int w = 0; w < TPB / 64; ++w) x += red[qq][w];
            partials[qq * NBLK + blockIdx.x] = x;
        }
    }
}

// ---------------- finalize: single wave, no barriers, float4 reads ----------------
__global__ __launch_bounds__(64) void bce_final(
    const float* __restrict__ partials, float* __restrict__ out)
{
    const int lane = threadIdx.x;   // 64 threads = 1 wave
    float acc[5] = {0.f, 0.f, 0.f, 0.f, 0.f};
#pragma unroll
    for (int qq = 0; qq < 5; ++qq) {
        const float4* src = reinterpret_cast<const float4*>(partials + qq * NBLK);
#pragma unroll
        for (int i = 0; i < 8; ++i) {
            const float4 x = src[i * 64 + lane];
            acc[qq] += (x.x + x.y) + (x.z + x.w);
        }
    }
#pragma unroll
    for (int qq = 0; qq < 5; ++qq) {
#pragma unroll
        for (int off = 32; off > 0; off >>= 1)
            acc[qq] += __shfl_down(acc[qq], off, 64);
    }
    if (lane == 0) {
        const float ce = acc[0], e0 = acc[1], e1 = acc[2], c0 = acc[3], c1 = acc[4];
        const float LN2  = 0.69314718055994530942f;
        const float invS = 1.f / (float)SPATIAL;
        const float ent0 = e0 * LN2 * invS;
        const float ent1 = e1 * LN2 * invS;
        const float m0   = (c0 == 0.f) ? 3.f : 1.f;   // all_bg -> MULT_UNLABELED
        const float m1   = (c1 == 0.f) ? 3.f : 1.f;
        out[0] = -(ce * LN2) / (float)(NB * SPATIAL);
        out[1] = -(m0 * ent0 + m1 * ent1) * 0.5f;
    }
}

extern "C" void kernel_launch(void* const* d_in, const int* in_sizes, int n_in,
                              void* d_out, int out_size, void* d_ws, size_t ws_size,
                              hipStream_t stream) {
    const float* probs  = (const float*)d_in[0];
    const int*   target = (const int*)d_in[1];
    const int*   ann    = (const int*)d_in[2];
    float*       out    = (float*)d_out;
    float*       partials = (float*)d_ws;   // 5 * NBLK * 4 B = 40 KiB

    bce_main<<<NBLK, TPB, 0, stream>>>(probs, target, ann, partials);
    bce_final<<<1, 64, 0, stream>>>(partials, out);
}